// Round 1
// baseline (3339.125 us; speedup 1.0000x reference)
//
#include <hip/hip_runtime.h>
#include <math.h>

#define NNODES 100000
#define NEDGES 3200000
#define NGRAPH 4096
#define HIDDEN 64
#define BN_EPS 1e-5f

// ---------------- degree / dinv ----------------
__global__ void k_init_deg(float* __restrict__ deg, int n) {
  int i = blockIdx.x * blockDim.x + threadIdx.x;
  if (i < n) deg[i] = 1.0f;  // self-loop
}

__global__ void k_deg_count(const int* __restrict__ dst, float* __restrict__ deg, int e) {
  int i = blockIdx.x * blockDim.x + threadIdx.x;
  int stride = gridDim.x * blockDim.x;
  for (; i < e; i += stride) atomicAdd(&deg[dst[i]], 1.0f);
}

__global__ void k_dinv(float* __restrict__ deg, int n) {
  int i = blockIdx.x * blockDim.x + threadIdx.x;
  if (i < n) deg[i] = 1.0f / sqrtf(deg[i]);
}

// ---------------- generic zero ----------------
__global__ void k_zero(float* __restrict__ p, int n) {
  int i = blockIdx.x * blockDim.x + threadIdx.x;
  int stride = gridDim.x * blockDim.x;
  for (; i < n; i += stride) p[i] = 0.0f;
}

// ---------------- [n,64] x [64,64] GEMM, optional bias+relu ----------------
// 256 threads, 64 rows per block. W staged in LDS (16KB), A rows staged (16KB).
template <bool RELU, bool BIAS>
__global__ void k_gemm64(const float* __restrict__ A, const float* __restrict__ W,
                         const float* __restrict__ b, float* __restrict__ C, int n) {
  __shared__ float Ws[64 * 64];
  __shared__ float As[64 * 64];
  __shared__ float bs[64];
  int t = threadIdx.x;
  for (int i = t; i < 64 * 64; i += 256) Ws[i] = W[i];
  if (BIAS && t < 64) bs[t] = b[t];
  int row0 = blockIdx.x * 64;
  int rows = min(64, n - row0);
  for (int i = t; i < rows * 64; i += 256) As[i] = A[row0 * 64 + i];
  __syncthreads();
  int c = t & 63;
  for (int r = (t >> 6); r < rows; r += 4) {
    float acc = BIAS ? bs[c] : 0.0f;
#pragma unroll
    for (int k = 0; k < 64; ++k) acc = fmaf(As[r * 64 + k], Ws[k * 64 + c], acc);
    if (RELU) acc = fmaxf(acc, 0.0f);
    C[(row0 + r) * 64 + c] = acc;
  }
}

// ---------------- agg init: agg[i] = dinv[i]^2 * xl[i] (self loop term) ----------------
__global__ void k_agg_init(const float* __restrict__ xl, const float* __restrict__ dinv,
                           float* __restrict__ agg, int n) {
  int i = blockIdx.x * blockDim.x + threadIdx.x;
  int stride = gridDim.x * blockDim.x;
  int total = n * HIDDEN;
  for (; i < total; i += stride) {
    int node = i >> 6;
    float di = dinv[node];
    agg[i] = di * di * xl[i];
  }
}

// ---------------- edge scatter: one wave per edge, lane = channel ----------------
__global__ void k_edge_scatter(const int* __restrict__ src, const int* __restrict__ dst,
                               const float* __restrict__ dinv, const float* __restrict__ xl,
                               float* __restrict__ agg, int e) {
  int lane = threadIdx.x & 63;
  int wave = (blockIdx.x * (blockDim.x >> 6)) + (threadIdx.x >> 6);
  int nwaves = gridDim.x * (blockDim.x >> 6);
  for (int ed = wave; ed < e; ed += nwaves) {
    int s = src[ed];
    int d = dst[ed];
    float norm = dinv[s] * dinv[d];
    float v = xl[s * 64 + lane] * norm;
    atomicAdd(&agg[d * 64 + lane], v);
  }
}

// ---------------- BN stats: per-channel sum & sumsq ----------------
__global__ void k_bn_stats(const float* __restrict__ D, float* __restrict__ stats, int n) {
  int c = threadIdx.x & 63;
  int rg = threadIdx.x >> 6;  // 0..3
  float s = 0.0f, q = 0.0f;
  for (int r = blockIdx.x * 4 + rg; r < n; r += gridDim.x * 4) {
    float v = D[r * 64 + c];
    s += v;
    q = fmaf(v, v, q);
  }
  __shared__ float ls[256], lq[256];
  ls[threadIdx.x] = s;
  lq[threadIdx.x] = q;
  __syncthreads();
  if (threadIdx.x < 64) {
    float S = ls[c] + ls[64 + c] + ls[128 + c] + ls[192 + c];
    float Q = lq[c] + lq[64 + c] + lq[128 + c] + lq[192 + c];
    atomicAdd(&stats[c], S);
    atomicAdd(&stats[64 + c], Q);
  }
}

// ---------------- BN apply + relu (+ optional residual) ----------------
template <bool RES>
__global__ void k_bn_apply(const float* __restrict__ D, const float* __restrict__ stats,
                           const float* __restrict__ g, const float* __restrict__ bb,
                           const float* __restrict__ x0, float* __restrict__ out, int n) {
  int i = blockIdx.x * blockDim.x + threadIdx.x;
  int stride = gridDim.x * blockDim.x;
  int total = n * HIDDEN;
  float inv_n = 1.0f / (float)n;
  for (; i < total; i += stride) {
    int c = i & 63;
    float mu = stats[c] * inv_n;
    float var = stats[64 + c] * inv_n - mu * mu;
    float sc = g[c] / sqrtf(var + BN_EPS);
    float v = (D[i] - mu) * sc + bb[c];
    v = fmaxf(v, 0.0f);
    if (RES) v += x0[i];
    out[i] = v;
  }
}

// ---------------- pool: atomic per (node, channel); counts per node ----------------
__global__ void k_pool(const float* __restrict__ h, const int* __restrict__ batch,
                       float* __restrict__ psum, float* __restrict__ pcnt, int n) {
  int lane = threadIdx.x & 63;
  int wave = (blockIdx.x * (blockDim.x >> 6)) + (threadIdx.x >> 6);
  int nwaves = gridDim.x * (blockDim.x >> 6);
  for (int node = wave; node < n; node += nwaves) {
    int gidx = batch[node];
    atomicAdd(&psum[gidx * 64 + lane], h[node * 64 + lane]);
    if (lane == 0) atomicAdd(&pcnt[gidx], 1.0f);
  }
}

// ---------------- head MLP: one block (64 threads) per graph ----------------
__global__ void k_head(const float* __restrict__ psum, const float* __restrict__ pcnt,
                       const float* __restrict__ W1, const float* __restrict__ b1,
                       const float* __restrict__ W2, const float* __restrict__ b2,
                       float* __restrict__ out) {
  int gidx = blockIdx.x;
  int t = threadIdx.x;
  __shared__ float pooled[64];
  __shared__ float hid[32];
  float cnt = fmaxf(pcnt[gidx], 1.0f);
  pooled[t] = psum[gidx * 64 + t] / cnt;
  __syncthreads();
  if (t < 32) {
    float a = b1[t];
#pragma unroll
    for (int k = 0; k < 64; ++k) a = fmaf(pooled[k], W1[k * 32 + t], a);
    hid[t] = fmaxf(a, 0.0f);
  }
  __syncthreads();
  if (t == 0) {
    float o = b2[0];
#pragma unroll
    for (int j = 0; j < 32; ++j) o = fmaf(hid[j], W2[j], o);
    out[gidx] = o;
  }
}

extern "C" void kernel_launch(void* const* d_in, const int* in_sizes, int n_in,
                              void* d_out, int out_size, void* d_ws, size_t ws_size,
                              hipStream_t stream) {
  const float* x       = (const float*)d_in[0];
  const int*   eidx    = (const int*)d_in[1];   // [2, E]: row0 = src, row1 = dst
  const int*   batch   = (const int*)d_in[2];
  const float* proj_W  = (const float*)d_in[3];
  const float* proj_b  = (const float*)d_in[4];
  const float* conv1_W = (const float*)d_in[5];
  const float* conv2_W = (const float*)d_in[7];
  const float* conv3_W = (const float*)d_in[9];
  const float* bn1_g   = (const float*)d_in[11];
  const float* bn1_b   = (const float*)d_in[12];
  const float* bn2_g   = (const float*)d_in[13];
  const float* bn2_b   = (const float*)d_in[14];
  const float* bn3_g   = (const float*)d_in[15];
  const float* bn3_b   = (const float*)d_in[16];
  const float* head_W1 = (const float*)d_in[17];
  const float* head_b1 = (const float*)d_in[18];
  const float* head_W2 = (const float*)d_in[19];
  const float* head_b2 = (const float*)d_in[20];
  float* out = (float*)d_out;

  const int N = NNODES, E = NEDGES, G = NGRAPH;
  const int* src = eidx;
  const int* dst = eidx + E;

  float* ws = (float*)d_ws;
  float* deg   = ws;                   // N  (becomes dinv in place)
  float* x0    = deg + N;              // N*64
  float* hb    = x0 + (size_t)N * 64;  // N*64
  float* xl    = hb + (size_t)N * 64;  // N*64
  float* ag    = xl + (size_t)N * 64;  // N*64
  float* stats = ag + (size_t)N * 64;  // 128
  float* psum  = stats + 128;          // G*64
  float* pcnt  = psum + (size_t)G * 64;  // G

  const int TB = 256;
  int gemm_grid = (N + 63) / 64;
  int ew_grid = 2048;   // waves = 8192, grid-stride over edges
  int el_grid = 2048;   // elementwise grid-stride over N*64

  // degree -> dinv
  k_init_deg<<<(N + TB - 1) / TB, TB, 0, stream>>>(deg, N);
  k_deg_count<<<2048, TB, 0, stream>>>(dst, deg, E);
  k_dinv<<<(N + TB - 1) / TB, TB, 0, stream>>>(deg, N);

  // x0 = relu(x @ proj_W + proj_b)
  k_gemm64<true, true><<<gemm_grid, TB, 0, stream>>>(x, proj_W, proj_b, x0, N);

  // ---- layer 1 ----
  k_gemm64<false, false><<<gemm_grid, TB, 0, stream>>>(x0, conv1_W, nullptr, xl, N);
  k_agg_init<<<el_grid, TB, 0, stream>>>(xl, deg, ag, N);
  k_edge_scatter<<<ew_grid, TB, 0, stream>>>(src, dst, deg, xl, ag, E);
  k_zero<<<1, 128, 0, stream>>>(stats, 128);
  k_bn_stats<<<512, TB, 0, stream>>>(ag, stats, N);
  k_bn_apply<false><<<el_grid, TB, 0, stream>>>(ag, stats, bn1_g, bn1_b, nullptr, hb, N);

  // ---- layer 2 (residual + x0 after relu) ----
  k_gemm64<false, false><<<gemm_grid, TB, 0, stream>>>(hb, conv2_W, nullptr, xl, N);
  k_agg_init<<<el_grid, TB, 0, stream>>>(xl, deg, ag, N);
  k_edge_scatter<<<ew_grid, TB, 0, stream>>>(src, dst, deg, xl, ag, E);
  k_zero<<<1, 128, 0, stream>>>(stats, 128);
  k_bn_stats<<<512, TB, 0, stream>>>(ag, stats, N);
  k_bn_apply<true><<<el_grid, TB, 0, stream>>>(ag, stats, bn2_g, bn2_b, x0, hb, N);

  // ---- layer 3 ----
  k_gemm64<false, false><<<gemm_grid, TB, 0, stream>>>(hb, conv3_W, nullptr, xl, N);
  k_agg_init<<<el_grid, TB, 0, stream>>>(xl, deg, ag, N);
  k_edge_scatter<<<ew_grid, TB, 0, stream>>>(src, dst, deg, xl, ag, E);
  k_zero<<<1, 128, 0, stream>>>(stats, 128);
  k_bn_stats<<<512, TB, 0, stream>>>(ag, stats, N);
  k_bn_apply<false><<<el_grid, TB, 0, stream>>>(ag, stats, bn3_g, bn3_b, nullptr, hb, N);

  // ---- pool + head ----
  k_zero<<<(G * 64 + G + TB - 1) / TB, TB, 0, stream>>>(psum, G * 64 + G);  // psum then pcnt contiguous
  k_pool<<<1024, TB, 0, stream>>>(hb, batch, psum, pcnt, N);
  k_head<<<G, 64, 0, stream>>>(psum, pcnt, head_W1, head_b1, head_W2, head_b2, out);
}

// Round 2
// 1944.676 us; speedup vs baseline: 1.7171x; 1.7171x over previous
//
#include <hip/hip_runtime.h>
#include <math.h>

#define NNODES 100000
#define NEDGES 3200000
#define NGRAPH 4096
#define BN_EPS 1e-5f
#define INV_N (1.0f / 100000.0f)
#define NB_SCAN 391  // ceil(100000/256)

// ---------------- zero helpers ----------------
__global__ void k_zero_i(int* __restrict__ p, int n) {
  int i = blockIdx.x * blockDim.x + threadIdx.x;
  int st = gridDim.x * blockDim.x;
  for (; i < n; i += st) p[i] = 0;
}
__global__ void k_zero_f(float* __restrict__ p, int n) {
  int i = blockIdx.x * blockDim.x + threadIdx.x;
  int st = gridDim.x * blockDim.x;
  for (; i < n; i += st) p[i] = 0.0f;
}

// ---------------- CSR build ----------------
__global__ void k_hist(const int* __restrict__ dst, int* __restrict__ cnt, int e) {
  int i = blockIdx.x * blockDim.x + threadIdx.x;
  int st = gridDim.x * blockDim.x;
  for (; i < e; i += st) atomicAdd(&cnt[dst[i]], 1);
}

__global__ void k_scan1(const int* __restrict__ cnt, int* __restrict__ tmp,
                        int* __restrict__ bsum, int n) {
  __shared__ int s[256];
  int i = blockIdx.x * 256 + threadIdx.x;
  int v = (i < n) ? cnt[i] : 0;
  s[threadIdx.x] = v;
  __syncthreads();
  for (int o = 1; o < 256; o <<= 1) {
    int x = (threadIdx.x >= o) ? s[threadIdx.x - o] : 0;
    __syncthreads();
    s[threadIdx.x] += x;
    __syncthreads();
  }
  if (i < n) tmp[i] = s[threadIdx.x];
  if (threadIdx.x == 255) bsum[blockIdx.x] = s[255];
}

__global__ void k_scan2(int* __restrict__ bsum, int nb) {
  __shared__ int s[512];
  int t = threadIdx.x;
  s[t] = (t < nb) ? bsum[t] : 0;
  __syncthreads();
  for (int o = 1; o < 512; o <<= 1) {
    int x = (t >= o) ? s[t - o] : 0;
    __syncthreads();
    s[t] += x;
    __syncthreads();
  }
  if (t < nb) bsum[t] = s[t];
}

__global__ void k_scan3(const int* __restrict__ tmp, const int* __restrict__ cnt,
                        const int* __restrict__ bsum, int* __restrict__ rowptr,
                        int* __restrict__ cursor, int n, int nb) {
  int i = blockIdx.x * 256 + threadIdx.x;
  if (i < n) {
    int b = i >> 8;
    int off = (b > 0) ? bsum[b - 1] : 0;
    int ex = tmp[i] - cnt[i] + off;
    rowptr[i] = ex;
    cursor[i] = ex;
    if (i == n - 1) rowptr[n] = bsum[nb - 1];
  }
}

__global__ void k_fill(const int* __restrict__ src, const int* __restrict__ dst,
                       int* __restrict__ cursor, int* __restrict__ col, int e) {
  int i = blockIdx.x * blockDim.x + threadIdx.x;
  int st = gridDim.x * blockDim.x;
  for (; i < e; i += st) {
    int d = dst[i];
    int pos = atomicAdd(&cursor[d], 1);
    col[pos] = src[i];
  }
}

__global__ void k_dinv(const int* __restrict__ cnt, float* __restrict__ dinv, int n) {
  int i = blockIdx.x * blockDim.x + threadIdx.x;
  if (i < n) dinv[i] = rsqrtf((float)cnt[i] + 1.0f);
}

// ---------------- [n,64] x [64,64] GEMM with fused BN prologue / scale epilogue ----
// PRO: 0 = none, 1 = BN+relu on A, 2 = BN+relu+residual on A
// EPI_DINV: multiply output row by dinv[row]; EPI_BR: bias + relu (proj layer)
template <int PRO, bool EPI_DINV, bool EPI_BR>
__global__ void k_gemm64(const float* __restrict__ A, const float* __restrict__ W,
                         const float* __restrict__ bias, const float* __restrict__ stats,
                         const float* __restrict__ g, const float* __restrict__ bb,
                         const float* __restrict__ res, const float* __restrict__ dinv,
                         float* __restrict__ C, int n) {
  __shared__ float Ws[64 * 64];
  __shared__ float As[64 * 64];
  __shared__ float scs[64], shs[64], bs[64];
  int t = threadIdx.x;
  for (int i = t; i < 64 * 64; i += 256) Ws[i] = W[i];
  if (t < 64) {
    if (EPI_BR) bs[t] = bias[t];
    if (PRO >= 1) {
      float mu = stats[t] * INV_N;
      float var = stats[64 + t] * INV_N - mu * mu;
      float sc = g[t] * rsqrtf(var + BN_EPS);
      scs[t] = sc;
      shs[t] = bb[t] - mu * sc;
    }
  }
  int row0 = blockIdx.x * 64;
  int rows = min(64, n - row0);
  __syncthreads();
  for (int i = t; i < rows * 64; i += 256) {
    float v = A[row0 * 64 + i];
    if (PRO >= 1) {
      int c = i & 63;
      v = fmaxf(fmaf(v, scs[c], shs[c]), 0.0f);
      if (PRO == 2) v += res[row0 * 64 + i];
    }
    As[i] = v;
  }
  __syncthreads();
  int c = t & 63;
  for (int r = (t >> 6); r < rows; r += 4) {
    float acc = EPI_BR ? bs[c] : 0.0f;
#pragma unroll
    for (int k = 0; k < 64; ++k) acc = fmaf(As[r * 64 + k], Ws[k * 64 + c], acc);
    if (EPI_BR) acc = fmaxf(acc, 0.0f);
    if (EPI_DINV) acc *= dinv[row0 + r];
    C[(row0 + r) * 64 + c] = acc;
  }
}

// ---------------- CSR gather aggregation + fused BN stats ----------------
// one wave per node (lane = channel): agg[d] = dinv[d] * (y[d] + sum y[src])
__global__ void k_aggregate(const int* __restrict__ rowptr, const int* __restrict__ col,
                            const float* __restrict__ y, const float* __restrict__ dinv,
                            float* __restrict__ ag, float* __restrict__ stats) {
  int lane = threadIdx.x & 63;
  int wave = blockIdx.x * (blockDim.x >> 6) + (threadIdx.x >> 6);
  int nw = gridDim.x * (blockDim.x >> 6);
  float s = 0.0f, q = 0.0f;
  for (int node = wave; node < NNODES; node += nw) {
    int rp = rowptr[node];
    int re = rowptr[node + 1];
    float acc = y[node * 64 + lane];  // self-loop term
    for (int base = rp; base < re; base += 64) {
      int rem = re - base;
      int m = rem < 64 ? rem : 64;
      int myi = (lane < rem) ? col[base + lane] : 0;
      int k = 0;
      for (; k + 4 <= m; k += 4) {
        int s0 = __shfl(myi, k);
        int s1 = __shfl(myi, k + 1);
        int s2 = __shfl(myi, k + 2);
        int s3 = __shfl(myi, k + 3);
        float v0 = y[s0 * 64 + lane];
        float v1 = y[s1 * 64 + lane];
        float v2 = y[s2 * 64 + lane];
        float v3 = y[s3 * 64 + lane];
        acc += v0;
        acc += v1;
        acc += v2;
        acc += v3;
      }
      for (; k < m; ++k) acc += y[__shfl(myi, k) * 64 + lane];
    }
    float o = acc * dinv[node];
    ag[node * 64 + lane] = o;
    s += o;
    q = fmaf(o, o, q);
  }
  __shared__ float ls[256], lq[256];
  ls[threadIdx.x] = s;
  lq[threadIdx.x] = q;
  __syncthreads();
  if (threadIdx.x < 64) {
    float S = ls[lane] + ls[64 + lane] + ls[128 + lane] + ls[192 + lane];
    float Q = lq[lane] + lq[64 + lane] + lq[128 + lane] + lq[192 + lane];
    atomicAdd(&stats[lane], S);
    atomicAdd(&stats[64 + lane], Q);
  }
}

// ---------------- pool with fused BN3+relu ----------------
__global__ void k_pool_bn(const float* __restrict__ ag, const float* __restrict__ stats,
                          const float* __restrict__ g, const float* __restrict__ bb,
                          const int* __restrict__ batch, float* __restrict__ psum,
                          float* __restrict__ pcnt) {
  __shared__ float sc[64], sh[64];
  int t = threadIdx.x;
  int lane = t & 63;
  if (t < 64) {
    float mu = stats[t] * INV_N;
    float var = stats[64 + t] * INV_N - mu * mu;
    float s = g[t] * rsqrtf(var + BN_EPS);
    sc[t] = s;
    sh[t] = bb[t] - mu * s;
  }
  __syncthreads();
  int wave = blockIdx.x * (blockDim.x >> 6) + (t >> 6);
  int nw = gridDim.x * (blockDim.x >> 6);
  for (int node = wave; node < NNODES; node += nw) {
    float v = fmaxf(fmaf(ag[node * 64 + lane], sc[lane], sh[lane]), 0.0f);
    int gi = batch[node];
    atomicAdd(&psum[gi * 64 + lane], v);
    if (lane == 0) atomicAdd(&pcnt[gi], 1.0f);
  }
}

// ---------------- head MLP ----------------
__global__ void k_head(const float* __restrict__ psum, const float* __restrict__ pcnt,
                       const float* __restrict__ W1, const float* __restrict__ b1,
                       const float* __restrict__ W2, const float* __restrict__ b2,
                       float* __restrict__ out) {
  int gidx = blockIdx.x;
  int t = threadIdx.x;
  __shared__ float pooled[64];
  __shared__ float hid[32];
  float cnt = fmaxf(pcnt[gidx], 1.0f);
  pooled[t] = psum[gidx * 64 + t] / cnt;
  __syncthreads();
  if (t < 32) {
    float a = b1[t];
#pragma unroll
    for (int k = 0; k < 64; ++k) a = fmaf(pooled[k], W1[k * 32 + t], a);
    hid[t] = fmaxf(a, 0.0f);
  }
  __syncthreads();
  if (t == 0) {
    float o = b2[0];
#pragma unroll
    for (int j = 0; j < 32; ++j) o = fmaf(hid[j], W2[j], o);
    out[gidx] = o;
  }
}

extern "C" void kernel_launch(void* const* d_in, const int* in_sizes, int n_in,
                              void* d_out, int out_size, void* d_ws, size_t ws_size,
                              hipStream_t stream) {
  const float* x       = (const float*)d_in[0];
  const int*   eidx    = (const int*)d_in[1];
  const int*   batch   = (const int*)d_in[2];
  const float* proj_W  = (const float*)d_in[3];
  const float* proj_b  = (const float*)d_in[4];
  const float* conv1_W = (const float*)d_in[5];
  const float* conv2_W = (const float*)d_in[7];
  const float* conv3_W = (const float*)d_in[9];
  const float* bn1_g   = (const float*)d_in[11];
  const float* bn1_b   = (const float*)d_in[12];
  const float* bn2_g   = (const float*)d_in[13];
  const float* bn2_b   = (const float*)d_in[14];
  const float* bn3_g   = (const float*)d_in[15];
  const float* bn3_b   = (const float*)d_in[16];
  const float* head_W1 = (const float*)d_in[17];
  const float* head_b1 = (const float*)d_in[18];
  const float* head_W2 = (const float*)d_in[19];
  const float* head_b2 = (const float*)d_in[20];
  float* out = (float*)d_out;

  const int N = NNODES, E = NEDGES, G = NGRAPH;
  const int* src = eidx;
  const int* dst = eidx + E;

  // workspace layout (256B aligned segments)
  char* p = (char*)d_ws;
  auto align256 = [](size_t v) { return (v + 255) & ~(size_t)255; };
  int* cnt = (int*)p;        p += align256((size_t)N * 4);
  int* rowptr = (int*)p;     p += align256((size_t)(N + 1) * 4);
  int* cursor = (int*)p;     p += align256((size_t)N * 4);
  int* tmp = (int*)p;        p += align256((size_t)N * 4);
  int* bsum = (int*)p;       p += align256(512 * 4);
  int* col = (int*)p;        p += align256((size_t)E * 4);
  float* dinv = (float*)p;   p += align256((size_t)N * 4);
  float* x0 = (float*)p;     p += align256((size_t)N * 64 * 4);
  float* y = (float*)p;      p += align256((size_t)N * 64 * 4);
  float* ag = (float*)p;     p += align256((size_t)N * 64 * 4);
  float* stats1 = (float*)p; p += align256(128 * 4);
  float* stats2 = (float*)p; p += align256(128 * 4);
  float* stats3 = (float*)p; p += align256(128 * 4);
  float* psum = (float*)p;   p += align256((size_t)G * 64 * 4);
  float* pcnt = (float*)p;   p += align256((size_t)G * 4);

  const int TB = 256;
  int gemm_grid = (N + 63) / 64;

  // ---- CSR build + dinv ----
  k_zero_i<<<(N + TB - 1) / TB, TB, 0, stream>>>(cnt, N);
  k_hist<<<2048, TB, 0, stream>>>(dst, cnt, E);
  k_scan1<<<NB_SCAN, 256, 0, stream>>>(cnt, tmp, bsum, N);
  k_scan2<<<1, 512, 0, stream>>>(bsum, NB_SCAN);
  k_scan3<<<NB_SCAN, 256, 0, stream>>>(tmp, cnt, bsum, rowptr, cursor, N, NB_SCAN);
  k_dinv<<<(N + TB - 1) / TB, TB, 0, stream>>>(cnt, dinv, N);
  k_fill<<<2048, TB, 0, stream>>>(src, dst, cursor, col, E);

  // zero stats + pool buffers
  k_zero_f<<<2, 192, 0, stream>>>(stats1, 384);  // stats1..3 contiguous
  k_zero_f<<<(G * 64 + G + TB - 1) / TB, TB, 0, stream>>>(psum, G * 64 + G);

  // ---- proj: x0 = relu(x @ W + b) ----
  k_gemm64<0, false, true><<<gemm_grid, TB, 0, stream>>>(
      x, proj_W, proj_b, nullptr, nullptr, nullptr, nullptr, nullptr, x0, N);

  // ---- layer 1 ----
  k_gemm64<0, true, false><<<gemm_grid, TB, 0, stream>>>(
      x0, conv1_W, nullptr, nullptr, nullptr, nullptr, nullptr, dinv, y, N);
  k_aggregate<<<2048, TB, 0, stream>>>(rowptr, col, y, dinv, ag, stats1);

  // ---- layer 2 (BN1+relu fused into A-load) ----
  k_gemm64<1, true, false><<<gemm_grid, TB, 0, stream>>>(
      ag, conv2_W, nullptr, stats1, bn1_g, bn1_b, nullptr, dinv, y, N);
  k_aggregate<<<2048, TB, 0, stream>>>(rowptr, col, y, dinv, ag, stats2);

  // ---- layer 3 (BN2+relu+x0 residual fused into A-load) ----
  k_gemm64<2, true, false><<<gemm_grid, TB, 0, stream>>>(
      ag, conv3_W, nullptr, stats2, bn2_g, bn2_b, x0, dinv, y, N);
  k_aggregate<<<2048, TB, 0, stream>>>(rowptr, col, y, dinv, ag, stats3);

  // ---- pool (BN3+relu fused) + head ----
  k_pool_bn<<<1024, TB, 0, stream>>>(ag, stats3, bn3_g, bn3_b, batch, psum, pcnt);
  k_head<<<G, 64, 0, stream>>>(psum, pcnt, head_W1, head_b1, head_W2, head_b2, out);
}